// Round 1
// baseline (284.210 us; speedup 1.0000x reference)
//
#include <hip/hip_runtime.h>

// Problem constants (from reference)
#define BB 64
#define TT 8192
#define NH 8
#define HD 10
#define DD 80            // NH*HD floats per (b,t) row
#define RSQRT10 0.31622776601683794f

// ---------------------------------------------------------------------------
// K1: ksum[b][d] = sum over t of x[b][t][d]   (d = 0..79)
// Grid: BB * (TT/256) = 2048 blocks, 320 threads (5 waves).
// Each block handles one b and a 256-row chunk of T.
// Thread layout: c4 = tid%20 (which float4 column), r0 = tid/20 (row phase).
// Loads are fully contiguous (wave covers 1024 consecutive bytes).
// ---------------------------------------------------------------------------
__global__ __launch_bounds__(320) void ksum_kernel(const float* __restrict__ x,
                                                   float* __restrict__ gsum) {
    int chunk = blockIdx.x & 31;           // TT/256 = 32 chunks
    int b     = blockIdx.x >> 5;
    const float4* xp = (const float4*)(x + ((size_t)b * TT + (size_t)chunk * 256) * DD);

    int tid = threadIdx.x;
    int c4  = tid % 20;                    // float4 column 0..19
    int r0  = tid / 20;                    // 0..15

    float4 acc = make_float4(0.f, 0.f, 0.f, 0.f);
#pragma unroll
    for (int k = 0; k < 16; ++k) {
        float4 v = xp[(size_t)(r0 + k * 16) * 20 + c4];
        acc.x += v.x; acc.y += v.y; acc.z += v.z; acc.w += v.w;
    }

    __shared__ float red[320][4];
    red[tid][0] = acc.x; red[tid][1] = acc.y; red[tid][2] = acc.z; red[tid][3] = acc.w;
    __syncthreads();

    if (tid < DD) {                        // 80 reducer threads
        int cc4 = tid >> 2, comp = tid & 3;
        float s = 0.f;
#pragma unroll
        for (int rr = 0; rr < 16; ++rr) s += red[cc4 + 20 * rr][comp];
        atomicAdd(&gsum[b * DD + tid], s);
    }
}

// ---------------------------------------------------------------------------
// K2: out[b][h][t] = sum_d attn_d * q_d,  attn = softmax_d(tanh(q_d*ks_d))
// gate from the reference is softmax over a size-1 axis == 1.0 -> dead code.
// Grid: BB * (TT/64) = 8192 blocks, 256 threads.
// Stage 64 rows x 80 floats in LDS with stride 81 (2-way bank alias = free).
// Thread (g = tid>>6, r = tid&63): row r, heads 2g..2g+1.
// Per-wave g is uniform -> ks[] reads broadcast; stores are 256B contiguous.
// ---------------------------------------------------------------------------
__global__ __launch_bounds__(256) void attn_kernel(const float* __restrict__ x,
                                                   const float* __restrict__ gsum,
                                                   float* __restrict__ out) {
    int chunk = blockIdx.x & 127;          // TT/64 = 128 chunks
    int b     = blockIdx.x >> 7;
    int t0    = chunk * 64;

    __shared__ float xs[64 * 81];
    __shared__ float ks[DD];

    const float4* xp = (const float4*)(x + ((size_t)b * TT + (size_t)t0) * DD);
    int tid = threadIdx.x;

    // stage: 64 rows * 20 float4 = 1280 float4, 5 per thread, coalesced
#pragma unroll
    for (int k = 0; k < 5; ++k) {
        int f4  = tid + k * 256;
        float4 v = xp[f4];
        int row = f4 / 20;
        int col = (f4 % 20) * 4;
        float* dst = &xs[row * 81 + col];
        dst[0] = v.x; dst[1] = v.y; dst[2] = v.z; dst[3] = v.w;
    }
    if (tid < DD) ks[tid] = gsum[b * DD + tid] * RSQRT10;  // fold 1/sqrt(10)
    __syncthreads();

    int g = tid >> 6;                      // 0..3 -> heads 2g, 2g+1
    int r = tid & 63;
    int t = t0 + r;
    const float* qrow = &xs[r * 81 + g * 20];

#pragma unroll
    for (int hh = 0; hh < 2; ++hh) {
        int h = g * 2 + hh;
        float esum = 0.f, eq = 0.f;
#pragma unroll
        for (int d = 0; d < 10; ++d) {
            float q = qrow[hh * 10 + d];
            float s = tanhf(q * ks[h * HD + d]);   // tanh in (-1,1): no max-sub needed
            float e = expf(s);
            esum += e;
            eq   += e * q;
        }
        out[((size_t)(b * NH + h)) * TT + t] = eq / esum;
    }
}

extern "C" void kernel_launch(void* const* d_in, const int* in_sizes, int n_in,
                              void* d_out, int out_size, void* d_ws, size_t ws_size,
                              hipStream_t stream) {
    const float* x = (const float*)d_in[0];
    // d_in[1] (w_proj) / d_in[2] (b_proj) are dead: softmax over size-1 axis == 1
    float* out  = (float*)d_out;
    float* gsum = (float*)d_ws;            // BB*DD floats = 20 KiB accumulator

    hipMemsetAsync(gsum, 0, BB * DD * sizeof(float), stream);
    ksum_kernel<<<dim3(BB * (TT / 256)), dim3(320), 0, stream>>>(x, gsum);
    attn_kernel<<<dim3(BB * (TT / 64)), dim3(256), 0, stream>>>(x, gsum, out);
}

// Round 2
// 262.643 us; speedup vs baseline: 1.0821x; 1.0821x over previous
//
#include <hip/hip_runtime.h>
#include <math.h>

// Problem constants (from reference)
#define BB 64
#define TT 8192
#define NH 8
#define HD 10
#define DD 80            // NH*HD floats per (b,t) row
#define NCHUNK 32        // K1: T-chunks per b (TT/256)
#define RSQRT10 0.31622776601683794f

// ---------------------------------------------------------------------------
// K1: per-(b,chunk) partial column sums of x, race-free (no memset/atomics).
// gpart[(b*32+chunk)*80 + d] = sum over the chunk's 256 rows of x[b][t][d].
// Grid: 2048 blocks x 320 threads; each wave's loads are 1KB contiguous.
// ---------------------------------------------------------------------------
__global__ __launch_bounds__(320) void ksum_kernel(const float* __restrict__ x,
                                                   float* __restrict__ gpart) {
    int chunk = blockIdx.x & (NCHUNK - 1);
    int b     = blockIdx.x >> 5;
    const float4* xp = (const float4*)(x + ((size_t)b * TT + (size_t)chunk * 256) * DD);

    int tid = threadIdx.x;
    int c4  = tid % 20;                    // float4 column 0..19
    int r0  = tid / 20;                    // row phase 0..15

    float4 acc = make_float4(0.f, 0.f, 0.f, 0.f);
#pragma unroll
    for (int k = 0; k < 16; ++k) {
        float4 v = xp[(size_t)(r0 + k * 16) * 20 + c4];
        acc.x += v.x; acc.y += v.y; acc.z += v.z; acc.w += v.w;
    }

    __shared__ float red[320][4];
    red[tid][0] = acc.x; red[tid][1] = acc.y; red[tid][2] = acc.z; red[tid][3] = acc.w;
    __syncthreads();

    if (tid < DD) {                        // 80 reducer threads, plain store
        int cc4 = tid >> 2, comp = tid & 3;
        float s = 0.f;
#pragma unroll
        for (int rr = 0; rr < 16; ++rr) s += red[cc4 + 20 * rr][comp];
        gpart[(b * NCHUNK + chunk) * DD + tid] = s;
    }
}

// ---------------------------------------------------------------------------
// K2: out[b][h][t] = sum_d e_d * q_d / sum_d e_d,  e = exp(tanh(q*ksum/sqrt(10)))
// (reference's gate = softmax over size-1 axis == 1.0 -> dead code)
// Fast branch-free tanh: sign * (1-e^-2a)/(1+e^-2a), a=|s|  -> 2 v_exp + 1 v_rcp.
// tanh in (-1,1) -> exp in (0.37,2.72): softmax needs no max subtraction.
// Grid: 8192 blocks x 256 threads; 64 rows staged in LDS (stride 81: reads are
// a bank permutation). Per-wave head-group g is uniform -> ks reads broadcast;
// stores are 256B contiguous per head.
// ---------------------------------------------------------------------------
__global__ __launch_bounds__(256) void attn_kernel(const float* __restrict__ x,
                                                   const float* __restrict__ gpart,
                                                   float* __restrict__ out) {
    int chunk = blockIdx.x & 127;          // TT/64 = 128 chunks
    int b     = blockIdx.x >> 7;
    int t0    = chunk * 64;

    __shared__ float xs[64 * 81];
    __shared__ float ks[DD];

    const float4* xp = (const float4*)(x + ((size_t)b * TT + (size_t)t0) * DD);
    int tid = threadIdx.x;

    // stage: 64 rows * 20 float4 = 1280 float4, 5 per thread, coalesced
#pragma unroll
    for (int k = 0; k < 5; ++k) {
        int f4  = tid + k * 256;
        float4 v = xp[f4];
        int row = f4 / 20;
        int col = (f4 % 20) * 4;
        float* dst = &xs[row * 81 + col];
        dst[0] = v.x; dst[1] = v.y; dst[2] = v.z; dst[3] = v.w;
    }
    if (tid < DD) {                        // reduce 32 partials (L2-resident)
        float s = 0.f;
#pragma unroll
        for (int c = 0; c < NCHUNK; ++c) s += gpart[(b * NCHUNK + c) * DD + tid];
        ks[tid] = s * RSQRT10;             // fold 1/sqrt(10)
    }
    __syncthreads();

    int g = tid >> 6;                      // 0..3 -> heads 2g, 2g+1
    int r = tid & 63;
    int t = t0 + r;
    const float* qrow = &xs[r * 81 + g * 20];

#pragma unroll
    for (int hh = 0; hh < 2; ++hh) {
        int h = g * 2 + hh;
        float esum = 0.f, eq = 0.f;
#pragma unroll
        for (int d = 0; d < 10; ++d) {
            float q  = qrow[hh * 10 + d];
            float sv = q * ks[h * HD + d];
            // stable fast tanh: no overflow (e^-2a in (0,1])
            float a  = fabsf(sv);
            float ex = __expf(-2.f * a);
            float th = copysignf((1.f - ex) * __builtin_amdgcn_rcpf(1.f + ex), sv);
            float e  = __expf(th);
            esum += e;
            eq   += e * q;
        }
        out[((size_t)(b * NH + h)) * TT + t] = eq * __builtin_amdgcn_rcpf(esum);
    }
}

extern "C" void kernel_launch(void* const* d_in, const int* in_sizes, int n_in,
                              void* d_out, int out_size, void* d_ws, size_t ws_size,
                              hipStream_t stream) {
    const float* x = (const float*)d_in[0];
    // d_in[1] (w_proj) / d_in[2] (b_proj) are dead: softmax over size-1 axis == 1
    float* out   = (float*)d_out;
    float* gpart = (float*)d_ws;           // BB*NCHUNK*DD floats = 640 KiB partials

    ksum_kernel<<<dim3(BB * NCHUNK), dim3(320), 0, stream>>>(x, gpart);
    attn_kernel<<<dim3(BB * (TT / 64)), dim3(256), 0, stream>>>(x, gpart, out);
}